// Round 1
// baseline (459.952 us; speedup 1.0000x reference)
//
#include <hip/hip_runtime.h>
#include <math.h>

// ---------------------------------------------------------------------------
// AttentionNet weighted-anchor aggregator.
//   x:  (8, 448, 448, 3) f32
//   wp3:(8, 6, 4, 14, 14) f32   wp4:(8, 6, 4, 7, 7) f32   wp5:(8, 9, 4, 4, 4) f32
//   out:(32, 224, 224, 3) f32 = sum over 21 configs of
//        resize_bilinear( einsum('bkij,bihjwc->bkhwc', w, patches), 224,224 )
// Two-phase: (A) agg into d_ws, (B) resize+accumulate into d_out.
// ---------------------------------------------------------------------------

#define BATCH 8
#define KK 4
#define OUT_HW 224
#define IMG_HW 448
#define NCFG 21

struct CfgEntry {
    int kh, kw;          // patch kernel size
    int stride;
    int p0, p1;          // padding
    int gh, gw;          // weight grid
    int layer;           // 0=p3, 1=p4, 2=p5
    int anchor;          // anchor index within layer
    int ws_off;          // float offset of this config's agg in ws
    int block_start;     // first block of this config in agg_kernel grid
    int blocks_per_img;  // ceil(kh*kw/256)
};

struct GroupArgs {
    CfgEntry e[NCFG];
    int n;
};

// ---------------------------------------------------------------------------
// Phase A: agg[bk, h, w, c] = sum_{i,j} W[b,k,i,j] * X[b, i*s+h-p0, j*s+w-p1, c]
// (zero outside image). One thread per (b, h, w), all 4 k and 3 c.
// ---------------------------------------------------------------------------
__global__ __launch_bounds__(256) void agg_kernel(
        const float* __restrict__ x,
        const float* __restrict__ wp3,
        const float* __restrict__ wp4,
        const float* __restrict__ wp5,
        float* __restrict__ ws,
        GroupArgs g) {
    // locate config for this block (<=21 entries, uniform scalar loop)
    int bid = blockIdx.x;
    int ci = 0;
    while (ci + 1 < g.n && bid >= g.e[ci + 1].block_start) ci++;
    const CfgEntry c = g.e[ci];

    int local = bid - c.block_start;
    int b     = local / c.blocks_per_img;
    int sblk  = local - b * c.blocks_per_img;
    int gsz   = c.gh * c.gw;

    const float* wsrc;
    if (c.layer == 0)      wsrc = wp3 + (size_t)(b * 6 + c.anchor) * (KK * 14 * 14);
    else if (c.layer == 1) wsrc = wp4 + (size_t)(b * 6 + c.anchor) * (KK * 7 * 7);
    else                   wsrc = wp5 + (size_t)(b * 9 + c.anchor) * (KK * 4 * 4);

    __shared__ float lw[KK * 14 * 14];   // max 784 floats
    for (int t = threadIdx.x; t < KK * gsz; t += blockDim.x) lw[t] = wsrc[t];
    __syncthreads();

    int npix = c.kh * c.kw;
    int idx  = sblk * 256 + threadIdx.x;
    if (idx >= npix) return;

    int h = idx / c.kw;
    int w = idx - h * c.kw;

    float acc[KK][3];
#pragma unroll
    for (int k = 0; k < KK; ++k) { acc[k][0] = 0.f; acc[k][1] = 0.f; acc[k][2] = 0.f; }

    int rowb = h - c.p0;
    int colb = w - c.p1;
    for (int i = 0; i < c.gh; ++i) {
        int row = rowb + i * c.stride;
        if ((unsigned)row >= (unsigned)IMG_HW) continue;
        const float* xrow = x + ((size_t)b * IMG_HW + row) * (IMG_HW * 3);
        for (int j = 0; j < c.gw; ++j) {
            int col = colb + j * c.stride;
            if ((unsigned)col >= (unsigned)IMG_HW) continue;
            const float* xp = xrow + col * 3;
            float x0 = xp[0], x1 = xp[1], x2 = xp[2];
            int wi = i * c.gw + j;
#pragma unroll
            for (int k = 0; k < KK; ++k) {
                float wv = lw[k * gsz + wi];
                acc[k][0] = fmaf(wv, x0, acc[k][0]);
                acc[k][1] = fmaf(wv, x1, acc[k][1]);
                acc[k][2] = fmaf(wv, x2, acc[k][2]);
            }
        }
    }

#pragma unroll
    for (int k = 0; k < KK; ++k) {
        size_t o = (size_t)c.ws_off + (((size_t)(b * KK + k) * npix) + idx) * 3;
        ws[o + 0] = acc[k][0];
        ws[o + 1] = acc[k][1];
        ws[o + 2] = acc[k][2];
    }
}

// ---------------------------------------------------------------------------
// Phase B: out[bk,y,x,c] (+)= sum_cfg sum_{i,j taps} RH[y,i]*RW[x,j]*agg[bk,i,j,c]
// jax.image.resize('bilinear', antialias=True) semantics:
//   inv = in/out; ks = max(inv,1); sf = (o+0.5)*inv - 0.5
//   w_i = max(0, 1 - |i-sf|/ks), normalized by sum over i in [0,in)
//   (edge-zero rule sf<-0.5 || sf>in-0.5 never triggers for these shapes)
// ---------------------------------------------------------------------------
__global__ __launch_bounds__(256) void resize_kernel(
        const float* __restrict__ ws,
        float* __restrict__ out,
        GroupArgs g, int accumulate) {
    int t = blockIdx.x * 256 + threadIdx.x;
    const int total = BATCH * KK * OUT_HW * OUT_HW;
    if (t >= total) return;

    int xo = t % OUT_HW;
    int yo = (t / OUT_HW) % OUT_HW;
    int bk = t / (OUT_HW * OUT_HW);

    size_t obase = (size_t)t * 3;
    float a0, a1, a2;
    if (accumulate) { a0 = out[obase]; a1 = out[obase + 1]; a2 = out[obase + 2]; }
    else            { a0 = 0.f; a1 = 0.f; a2 = 0.f; }

    for (int ci = 0; ci < g.n; ++ci) {
        const int kh = g.e[ci].kh;
        const int kw = g.e[ci].kw;
        const int ws_off = g.e[ci].ws_off;

        // H taps
        float invh = (float)(1.0 / ((double)OUT_HW / (double)kh));
        float ksh  = invh > 1.f ? invh : 1.f;
        float rksh = 1.f / ksh;
        float sfh  = ((float)yo + 0.5f) * invh - 0.5f;
        int i0 = (int)ceilf(sfh - ksh);  if (i0 < 0) i0 = 0;
        int i1 = (int)floorf(sfh + ksh); if (i1 > kh - 1) i1 = kh - 1;
        float sumh = 0.f;
        for (int i = i0; i <= i1; ++i) {
            float v = 1.f - fabsf((float)i - sfh) * rksh;
            sumh += (v > 0.f ? v : 0.f);
        }

        // W taps
        float invw = (float)(1.0 / ((double)OUT_HW / (double)kw));
        float ksw  = invw > 1.f ? invw : 1.f;
        float rksw = 1.f / ksw;
        float sfw  = ((float)xo + 0.5f) * invw - 0.5f;
        int j0 = (int)ceilf(sfw - ksw);  if (j0 < 0) j0 = 0;
        int j1 = (int)floorf(sfw + ksw); if (j1 > kw - 1) j1 = kw - 1;
        float sumw = 0.f;
        for (int j = j0; j <= j1; ++j) {
            float v = 1.f - fabsf((float)j - sfw) * rksw;
            sumw += (v > 0.f ? v : 0.f);
        }

        const float* base = ws + (size_t)ws_off + (size_t)bk * kh * kw * 3;
        float s0 = 0.f, s1 = 0.f, s2 = 0.f;
        for (int i = i0; i <= i1; ++i) {
            float whv = 1.f - fabsf((float)i - sfh) * rksh;
            whv = (whv > 0.f ? whv : 0.f);
            const float* rp = base + ((size_t)i * kw + j0) * 3;
            float r0 = 0.f, r1 = 0.f, r2 = 0.f;
            float fj = (float)j0 - sfw;
            for (int j = j0; j <= j1; ++j) {
                float wv = 1.f - fabsf(fj) * rksw;
                wv = (wv > 0.f ? wv : 0.f);
                r0 = fmaf(wv, rp[0], r0);
                r1 = fmaf(wv, rp[1], r1);
                r2 = fmaf(wv, rp[2], r2);
                rp += 3;
                fj += 1.f;
            }
            s0 = fmaf(whv, r0, s0);
            s1 = fmaf(whv, r1, s1);
            s2 = fmaf(whv, r2, s2);
        }
        float norm = 1.f / (sumh * sumw);
        a0 = fmaf(s0, norm, a0);
        a1 = fmaf(s1, norm, a1);
        a2 = fmaf(s2, norm, a2);
    }

    out[obase + 0] = a0;
    out[obase + 1] = a1;
    out[obase + 2] = a2;
}

// ---------------------------------------------------------------------------
// Host launch
// ---------------------------------------------------------------------------
extern "C" void kernel_launch(void* const* d_in, const int* in_sizes, int n_in,
                              void* d_out, int out_size, void* d_ws, size_t ws_size,
                              hipStream_t stream) {
    const float* x   = (const float*)d_in[0];
    const float* wp3 = (const float*)d_in[1];
    const float* wp4 = (const float*)d_in[2];
    const float* wp5 = (const float*)d_in[3];
    float* out = (float*)d_out;
    float* wsf = (float*)d_ws;

    // Build the 21 configs exactly as the reference does (double precision).
    struct { int stride, size, nscale; double scales[3]; int gh; } layers[3] = {
        {32, 48, 2, {pow(2.0, 1.0 / 3.0), pow(2.0, 2.0 / 3.0), 0.0}, 14},
        {64, 96, 2, {pow(2.0, 1.0 / 3.0), pow(2.0, 2.0 / 3.0), 0.0}, 7},
        {128, 192, 3, {1.0, pow(2.0, 1.0 / 3.0), pow(2.0, 2.0 / 3.0)}, 4},
    };
    const double ars[3] = {0.667, 1.0, 1.5};

    CfgEntry cfg[NCFG];
    int nc = 0;
    for (int L = 0; L < 3; ++L) {
        int anchor = 0;
        for (int si = 0; si < layers[L].nscale; ++si) {
            for (int ai = 0; ai < 3; ++ai) {
                double ss = (double)layers[L].size * layers[L].scales[si];
                double sq = pow(ars[ai], 0.5);
                int kh = (int)(ss / sq);
                int kw = (int)(ss * sq);
                CfgEntry& e = cfg[nc++];
                e.kh = kh; e.kw = kw;
                e.stride = layers[L].stride;
                e.p0 = (int)ceil((double)(kh - layers[L].stride) / 2.0);
                e.p1 = (int)ceil((double)(kw - layers[L].stride) / 2.0);
                e.gh = layers[L].gh; e.gw = layers[L].gh;
                e.layer = L; e.anchor = anchor++;
                e.ws_off = 0; e.block_start = 0;
                e.blocks_per_img = (kh * kw + 255) / 256;
            }
        }
    }

    // Greedy grouping by workspace capacity (capped at 128 MB for L3 locality).
    size_t cap_bytes = ws_size < (size_t)(128u * 1024u * 1024u) ? ws_size
                                                                : (size_t)(128u * 1024u * 1024u);
    size_t cap_floats = cap_bytes / 4;

    const int out_total  = BATCH * KK * OUT_HW * OUT_HW;
    const int out_blocks = (out_total + 255) / 256;

    int i = 0;
    int first = 1;
    while (i < NCFG) {
        GroupArgs g;
        g.n = 0;
        size_t used = 0;
        int blocks = 0;
        while (i < NCFG) {
            size_t need = (size_t)cfg[i].kh * cfg[i].kw * 3 * (BATCH * KK);
            if (g.n > 0 && used + need > cap_floats) break;
            CfgEntry e = cfg[i];
            e.ws_off = (int)used;
            e.block_start = blocks;
            blocks += e.blocks_per_img * BATCH;
            used += need;
            g.e[g.n++] = e;
            ++i;
            if (used >= cap_floats) break;
        }
        agg_kernel<<<blocks, 256, 0, stream>>>(x, wp3, wp4, wp5, wsf, g);
        resize_kernel<<<out_blocks, 256, 0, stream>>>(wsf, out, g, first ? 0 : 1);
        first = 0;
    }
}